// Round 3
// baseline (162.835 us; speedup 1.0000x reference)
//
#include <hip/hip_runtime.h>
#include <stdint.h>

// ---------------------------------------------------------------------------
// PoseFeatureExtractor fused kernel for MI355X (gfx950) — round 7
//   Consolidation: MT=64 (r4/r5 geometry, fastest measured) + r6's slim LDS
//   (zero-W boundary overrun, exact) + r6's obuf/NT full-line write epilogue
//   (WRITE_SIZE == 64MiB proven). Chain cuts: 0b+0d merged into one barrier
//   section; float2 staging (scalar prologue handles batch clamp); biases
//   folded into MFMA C-in. prep reindexed (k per block, coalesced).
// ---------------------------------------------------------------------------

#define S_    2048
#define MT_   64
#define TPB   512
#define HID_  256
#define OUT_  128
#define NTOK  131072                 // 64 * 2048 tokens
#define F_    66                     // staged frames per block (MT_+2)

typedef __attribute__((ext_vector_type(8))) _Float16 half8;   // fp16x8 MFMA frag
typedef __attribute__((ext_vector_type(4))) float    floatx4; // fp32x4 MFMA acc
typedef __attribute__((ext_vector_type(4))) float    f4_t;    // for NT stores

// edge tables packed as nibbles: c0[e] = (C0M>>4e)&15 ; c1[e] = ((C1M>>4e)&15)+1
#define C0M 0x0ECDB118675110ULL
#define C1M 0x0FDECBA9786540ULL

// |err| <= 6.7e-5 abs (A&S 4.4.45) — far below fp16 feature quantization
__device__ __forceinline__ float facos(float x) {
    float ax = fabsf(x);
    float p = fmaf(ax, -0.0187293f, 0.0742610f);
    p = fmaf(ax, p, -0.2121144f);
    p = fmaf(ax, p, 1.5707288f);
    float r = __builtin_amdgcn_sqrtf(1.f - ax) * p;
    return x < 0.f ? 3.14159265358979f - r : r;
}

// --------------------------- prep kernel -----------------------------------
// Build W1'' (BN-fold + temporal-fold + jw-fold), fp16, MFMA-B-fragment order.
// K layout: [cc(s) 0..95][cc(s-1) 96..191][cc(s-2) 192..287][ang 288..351]
//   d0 rows: (Wp+Wv+Wa)*a*jw ; d1: -(Wv+2Wa)*a*jw ; d2: Wa*a*jw ; ang: Wang*a*jw
// Rows loc>=75 (cc) / q>=39 (ang) are ZERO — the main kernel's A-reads that
// cross a frame boundary land on these rows (exactness requirement).
// Grid: blocks 0..351 = W1 row k; 352..479 = W2 (2 rows each); 480 = bias.
__global__ void prep_kernel(const float* __restrict__ W1, const float* __restrict__ b1,
                            const float* __restrict__ gamma, const float* __restrict__ beta,
                            const float* __restrict__ rmean, const float* __restrict__ rvar,
                            const float* __restrict__ W2, const float* __restrict__ jw,
                            _Float16* __restrict__ w1p,
                            _Float16* __restrict__ w2p,
                            float* __restrict__ b1p) {
    int bid = blockIdx.x, tid = threadIdx.x;
    if (bid < 352) {                         // W1'' row k = bid, n = tid
        int k = bid, n = tid;
        float a = gamma[n] * __builtin_amdgcn_rsqf(rvar[n] + 1e-5f);
        float v = 0.f;
        if (k < 288) {
            int d = k / 96, loc = k - d * 96;        // scalar (uniform) math
            if (loc < 75) {
                int j = loc / 3, c = loc - j * 3;
                const float* Wb = W1 + (j * 12 + c) * HID_ + n;
                float wp = Wb[0], wv = Wb[3 * HID_], wa = Wb[6 * HID_];
                float t = (d == 0) ? (wp + wv + wa) : (d == 1 ? -(wv + 2.f * wa) : wa);
                v = t * a * jw[j];
            }
        } else {
            int q = k - 288;
            if (q < 39) {
                int e = q / 3, aa = q - e * 3;
                v = W1[(e * 12 + 9 + aa) * HID_ + n] * a * jw[e];
            }
        }
        int blk = (k >> 5) * 16 + (n >> 4);
        int off = blk * 512 + (((k >> 3) & 3) * 16 + (n & 15)) * 8 + (k & 7);
        w1p[off] = (_Float16)v;
    } else if (bid < 480) {                  // W2 packed fp16, 2 rows/block
        int i2 = (bid - 352) * 256 + tid;
        int k = i2 >> 7, n = i2 & 127;
        int blk = (k >> 5) * 8 + (n >> 4);
        int off = blk * 512 + (((k >> 3) & 3) * 16 + (n & 15)) * 8 + (k & 7);
        w2p[off] = (_Float16)W2[k * OUT_ + n];
    } else {                                 // folded bias
        int n = tid;
        float a = gamma[n] * __builtin_amdgcn_rsqf(rvar[n] + 1e-5f);
        b1p[n] = fmaf(a, b1[n] - rmean[n], beta[n]);
    }
}

// --------------------------- main fused kernel ------------------------------
// LDS: ccb 66 x 88 halfs (+8 slack)  11632 B (176B rows -> 2-way, free)
//      ab  64 x 40 halfs (+24 slack)  5168 B ( 80B rows -> 2-way, free)
//      raw 4950 floats               19800 B (frames t0-2..t0+63)
//      rs  66 float4 (root, scale)    1056 B
//      hid (64 x 264 halfs = 33792B) and obuf (64 x 132 f32 = 33792B)
//      overlay [0..33792) (ccb+ab+raw) after GEMM1 / GEMM2.
#define L_CCB 0
#define L_AB  11632
#define L_RAW 16800
#define L_RS  36608
#define L_TOT 37696                  // 3 blocks/CU (wave-capped at lb 512,6)

__global__ __launch_bounds__(TPB, 6) void pose_mlp(
    const float* __restrict__ poses,
    const _Float16* __restrict__ w1p,
    const _Float16* __restrict__ w2p,
    const float* __restrict__ b1p,
    const float* __restrict__ b2,
    float* __restrict__ out)
{
    __shared__ __align__(16) unsigned char smem[L_TOT];
    const int tid  = threadIdx.x;
    const int lane = tid & 63;
    const int wv   = tid >> 6;               // 0..7
    const int t0   = blockIdx.x * MT_;
    const int s0   = t0 & (S_ - 1);

    _Float16* ccb = (_Float16*)(smem + L_CCB);
    _Float16* ab  = (_Float16*)(smem + L_AB);
    float*    raw = (float*)(smem + L_RAW);
    float4*   rs  = (float4*)(smem + L_RS);

    // early prefetch: GEMM1 kc=0 B-frags + biases (global, fly under stage)
    half8 bw[2];
    #pragma unroll
    for (int ni = 0; ni < 2; ni++)
        bw[ni] = *(const half8*)(w1p + (unsigned)(wv * 2 + ni) * 512 + lane * 8);
    float bv[2];
    #pragma unroll
    for (int ni = 0; ni < 2; ni++) bv[ni] = b1p[wv * 32 + ni * 16 + (lane & 15)];
    float c2 = b2[wv * 16 + (lane & 15)];

    // ---- stage: poses frames (t0-2..t0+63) -> LDS ----
    // scalar prologue (floats 0..151) absorbs the per-batch clamp (frames
    // -2,-1 -> frame 0 when s0==0); float2 main part is clamp-free.
    if (tid < 152) {
        int src = t0 * 75 - 150 + tid;
        if (s0 == 0) { if (tid < 75) src += 150; else if (tid < 150) src += 75; }
        raw[tid] = poses[src];
    }
    {
        const float2* ps = (const float2*)(poses + (size_t)t0 * 75 + 2);
        #pragma unroll 1
        for (int i = tid; i < 2399; i += TPB) {     // floats 152..4949
            float2 v = ps[i];
            *(float2*)(raw + 152 + 2 * i) = v;
        }
    }
    // zero constant-pad slots: ccb slack row (8), ab slack row (24), ab col39 (64)
    if (tid < 96) {
        if (tid < 8)       ccb[F_ * 88 + tid] = (_Float16)0.f;
        else if (tid < 32) ab[MT_ * 40 + (tid - 8)] = (_Float16)0.f;
        else               ab[(tid - 32) * 40 + 39] = (_Float16)0.f;
    }
    __syncthreads();

    // ---- 0d + 0b (both read only raw): one barrier section ----
    // 0d: joint angles -> ab fp16 (v/||v|| invariant to centering+scale)
    #pragma unroll
    for (int r2 = 0; r2 < 2; r2++) {
        int i = r2 * TPB + tid;              // 0..1023
        int tt = i >> 4, e = i & 15;
        if (e < 13) {
            const float* R = raw + (tt + 2) * 75;
            int a0 = (int)((C0M >> (4 * e)) & 15) * 3;
            int a1 = (((int)((C1M >> (4 * e)) & 15)) + 1) * 3;
            float vx = R[a1] - R[a0], vy = R[a1 + 1] - R[a0 + 1], vz = R[a1 + 2] - R[a0 + 2];
            float d  = fmaf(vx, vx, fmaf(vy, vy, vz * vz));
            float inv = __builtin_amdgcn_rcpf(fmaxf(__builtin_amdgcn_sqrtf(d), 1e-12f));
            _Float16* A = ab + tt * 40;
            A[e * 3 + 0] = (_Float16)facos(fminf(fmaxf(vx * inv, -1.f), 1.f));
            A[e * 3 + 1] = (_Float16)facos(fminf(fmaxf(vy * inv, -1.f), 1.f));
            A[e * 3 + 2] = (_Float16)facos(fminf(fmaxf(vz * inv, -1.f), 1.f));
        }
    }
    // 0b: root + scale per frame (66 frames x 4 lanes, 7-joint groups)
    if (tid < F_ * 4) {
        int f = tid >> 2, q = tid & 3;
        const float* R = raw + f * 75;
        float r0 = R[0], r1 = R[1], r2 = R[2];
        float m2 = 0.f;
        #pragma unroll
        for (int jj = 0; jj < 7; jj++) {
            int j = q * 7 + jj;
            if (j < 25) {
                float dx = R[j * 3]     - r0;
                float dy = R[j * 3 + 1] - r1;
                float dz = R[j * 3 + 2] - r2;
                m2 = fmaxf(m2, fmaf(dx, dx, fmaf(dy, dy, dz * dz)));
            }
        }
        m2 = fmaxf(m2, __shfl_xor(m2, 1));
        m2 = fmaxf(m2, __shfl_xor(m2, 2));
        if (q == 0) {
            float sc = __builtin_amdgcn_rcpf(__builtin_amdgcn_sqrtf(m2) + 1e-8f);
            rs[f] = make_float4(r0, r1, r2, sc);
        }
    }
    __syncthreads();

    // ---- 0c: center+scale -> ccb fp16 (j>=25 lanes zero cols 75..87) ----
    #pragma unroll 1
    for (int i = tid; i < F_ * 32; i += TPB) {
        int f = i >> 5, j = i & 31;
        _Float16* C = ccb + f * 88;
        if (j < 25) {
            const float* R = raw + f * 75 + j * 3;
            float4 q = rs[f];
            C[j * 3 + 0] = (_Float16)((R[0] - q.x) * q.w);
            C[j * 3 + 1] = (_Float16)((R[1] - q.y) * q.w);
            C[j * 3 + 2] = (_Float16)((R[2] - q.z) * q.w);
        } else {
            int c = 75 + (j - 25) * 2;
            C[c] = (_Float16)0.f;
            if (c + 1 < 88) C[c + 1] = (_Float16)0.f;
        }
    }
    __syncthreads();

    // ---- GEMM1: hid = relu(A @ W1'' + b1'); K=352; bias in MFMA C-in ----
    floatx4 acc[4][2];
    #pragma unroll
    for (int mi = 0; mi < 4; mi++)
        #pragma unroll
        for (int ni = 0; ni < 2; ni++)
            acc[mi][ni] = (floatx4){bv[ni], bv[ni], bv[ni], bv[ni]};

    int rowb[4];
    #pragma unroll
    for (int mi = 0; mi < 4; mi++)           // (token+2)*88 + (l>>4)*8
        rowb[mi] = (mi * 16 + (lane & 15) + 2) * 88 + (lane >> 4) * 8;

    int koff = 0;                            // 32*(kc%3) - 88*(kc/3)
    #pragma unroll 1
    for (int kc = 0; kc < 9; kc++) {         // cc regions d = kc/3
        half8 bn[2];
        #pragma unroll
        for (int ni = 0; ni < 2; ni++)
            bn[ni] = *(const half8*)(w1p + (unsigned)((kc + 1) * 16 + wv * 2 + ni) * 512 + lane * 8);
        half8 af[4];
        #pragma unroll
        for (int mi = 0; mi < 4; mi++)
            af[mi] = *(const half8*)(ccb + rowb[mi] + koff);
        #pragma unroll
        for (int mi = 0; mi < 4; mi++)
            #pragma unroll
            for (int ni = 0; ni < 2; ni++)
                acc[mi][ni] = __builtin_amdgcn_mfma_f32_16x16x32_f16(
                    af[mi], bw[ni], acc[mi][ni], 0, 0, 0);
        bw[0] = bn[0]; bw[1] = bn[1];
        koff += 32; if (kc == 2 || kc == 5) koff -= 184;   // next region
    }
    {   // kc = 9,10: angle region from ab
        int rowa[4];
        #pragma unroll
        for (int mi = 0; mi < 4; mi++)
            rowa[mi] = (mi * 16 + (lane & 15)) * 40 + (lane >> 4) * 8;
        #pragma unroll
        for (int kc = 9; kc < 11; kc++) {
            half8 bn[2];
            if (kc < 10) {
                #pragma unroll
                for (int ni = 0; ni < 2; ni++)
                    bn[ni] = *(const half8*)(w1p + (unsigned)((kc + 1) * 16 + wv * 2 + ni) * 512 + lane * 8);
            }
            half8 af[4];
            #pragma unroll
            for (int mi = 0; mi < 4; mi++)
                af[mi] = *(const half8*)(ab + rowa[mi] + (kc - 9) * 32);
            #pragma unroll
            for (int mi = 0; mi < 4; mi++)
                #pragma unroll
                for (int ni = 0; ni < 2; ni++)
                    acc[mi][ni] = __builtin_amdgcn_mfma_f32_16x16x32_f16(
                        af[mi], bw[ni], acc[mi][ni], 0, 0, 0);
            if (kc < 10) { bw[0] = bn[0]; bw[1] = bn[1]; }
        }
    }

    // preload W2 kc=0 frag (this wave's n-tile), independent of LDS
    half8 bw2 = *(const half8*)(w2p + (unsigned)wv * 512 + lane * 8);

    __syncthreads();   // all waves done reading ccb/ab/raw

    _Float16* hid = (_Float16*)smem;         // 64 x 264, overlays ccb/ab/raw
    #pragma unroll
    for (int mi = 0; mi < 4; mi++)
        #pragma unroll
        for (int ni = 0; ni < 2; ni++)
            #pragma unroll
            for (int r = 0; r < 4; r++) {
                float v = fmaxf(acc[mi][ni][r], 0.f);      // bias already in
                int m   = mi * 16 + (lane >> 4) * 4 + r;   // C/D: row=(l>>4)*4+r
                int col = wv * 32 + ni * 16 + (lane & 15); //      col=l&15
                hid[m * 264 + col] = (_Float16)v;
            }
    __syncthreads();   // hid visible

    // ---- GEMM2: out = hid @ W2 + b2; wave wv owns n-tile wv; b2 in C-in ----
    floatx4 acc2[4];
    #pragma unroll
    for (int mi = 0; mi < 4; mi++) acc2[mi] = (floatx4){c2, c2, c2, c2};

    #pragma unroll 1
    for (int kc = 0; kc < 8; kc++) {
        half8 bn2;
        if (kc < 7)
            bn2 = *(const half8*)(w2p + (unsigned)((kc + 1) * 8 + wv) * 512 + lane * 8);
        half8 af[4];
        #pragma unroll
        for (int mi = 0; mi < 4; mi++)
            af[mi] = *(const half8*)(hid + (mi * 16 + (lane & 15)) * 264 + kc * 32 + (lane >> 4) * 8);
        #pragma unroll
        for (int mi = 0; mi < 4; mi++)
            acc2[mi] = __builtin_amdgcn_mfma_f32_16x16x32_f16(
                af[mi], bw2, acc2[mi], 0, 0, 0);
        if (kc < 7) bw2 = bn2;
    }
    __syncthreads();   // all waves done reading hid

    // ---- epilogue: acc2 -> LDS fp32 (stride 132 -> 2-way free), then
    //      contiguous float4 NONTEMPORAL stores (full-line HBM writes) ----
    float* obuf = (float*)smem;              // 64 x 132 f32
    #pragma unroll
    for (int mi = 0; mi < 4; mi++)
        #pragma unroll
        for (int r = 0; r < 4; r++) {
            int m = mi * 16 + (lane >> 4) * 4 + r;
            obuf[m * 132 + wv * 16 + (lane & 15)] = acc2[mi][r];
        }
    __syncthreads();
    #pragma unroll
    for (int k = 0; k < 4; k++) {
        int idx = k * TPB + tid;             // 0..2047 float4s
        int row = idx >> 5, c4 = idx & 31;
        f4_t v = *(const f4_t*)(obuf + row * 132 + c4 * 4);
        __builtin_nontemporal_store(v, (f4_t*)out + (size_t)t0 * 32 + idx);
    }
}

// --------------------------- launch -----------------------------------------
extern "C" void kernel_launch(void* const* d_in, const int* in_sizes, int n_in,
                              void* d_out, int out_size, void* d_ws, size_t ws_size,
                              hipStream_t stream) {
    (void)in_sizes; (void)n_in; (void)out_size; (void)ws_size;
    const float* poses = (const float*)d_in[0];
    const float* W1    = (const float*)d_in[1];
    const float* b1    = (const float*)d_in[2];
    const float* gamma = (const float*)d_in[3];
    const float* beta  = (const float*)d_in[4];
    const float* rmean = (const float*)d_in[5];
    const float* rvar  = (const float*)d_in[6];
    const float* W2    = (const float*)d_in[7];
    const float* b2    = (const float*)d_in[8];
    const float* jw    = (const float*)d_in[9];

    _Float16* w1p = (_Float16*)d_ws;                         // 352*256 fp16
    _Float16* w2p = w1p + 352 * HID_;                        // 256*128 fp16
    float* b1p = (float*)((char*)d_ws + (352 * HID_ + HID_ * OUT_) * 2);

    prep_kernel<<<481, 256, 0, stream>>>(W1, b1, gamma, beta, rmean, rvar, W2, jw,
                                         w1p, w2p, b1p);
    pose_mlp<<<2048, TPB, 0, stream>>>(poses, w1p, w2p, b1p, b2, (float*)d_out);
}

// Round 4
// 146.858 us; speedup vs baseline: 1.1088x; 1.1088x over previous
//
#include <hip/hip_runtime.h>
#include <hip/hip_bf16.h>
#include <stdint.h>

// ---------------------------------------------------------------------------
// PoseFeatureExtractor fused kernel for MI355X (gfx950) — round 8
//   REVERT to round-4 structure (56 µs proven: no staging, direct global
//   phase-0 reads, bf16 MFMA, MT=64, 3 blocks/CU) + three isolated grafts:
//     1) 0a+0b merged into one shfl-reduce phase (one fewer barrier, no pm)
//     2) biases folded into MFMA C-in (exact, fp32 accumulate)
//     3) nontemporal epilogue stores (protect L2/L3-resident poses from
//        the 64 MiB output stream; segments are aligned 64B -> no RMW)
// ---------------------------------------------------------------------------

#define S_    2048
#define MT_   64
#define TPB   512
#define HID_  256
#define OUT_  128

typedef __attribute__((ext_vector_type(8))) short   short8;   // bf16x8 MFMA frag
typedef __attribute__((ext_vector_type(4))) float   floatx4;  // fp32x4 MFMA acc

// edge tables packed as nibbles: c0[e] = (C0M>>4e)&15 ; c1[e] = ((C1M>>4e)&15)+1
#define C0M 0x0ECDB118675110ULL
#define C1M 0x0FDECBA9786540ULL

__device__ __forceinline__ unsigned short bf16_bits(float v) {
    union { float f; unsigned u; } x; x.f = v;
    unsigned r = x.u + 0x7fffu + ((x.u >> 16) & 1u);   // RNE
    return (unsigned short)(r >> 16);
}

__device__ __forceinline__ unsigned pkbf16(float a, float b) {
#if __has_builtin(__builtin_amdgcn_cvt_pk_bf16_f32)
    auto v = __builtin_amdgcn_cvt_pk_bf16_f32(a, b);   // RNE, 1 instr
    unsigned u; __builtin_memcpy(&u, &v, 4); return u;
#else
    return (unsigned)bf16_bits(a) | ((unsigned)bf16_bits(b) << 16);
#endif
}

// |err| <= 6.7e-5 abs (A&S 4.4.45) — far below bf16 feature quantization
__device__ __forceinline__ float facos(float x) {
    float ax = fabsf(x);
    float p = fmaf(ax, -0.0187293f, 0.0742610f);
    p = fmaf(ax, p, -0.2121144f);
    p = fmaf(ax, p, 1.5707288f);
    float r = __builtin_amdgcn_sqrtf(1.f - ax) * p;
    return x < 0.f ? 3.14159265358979f - r : r;
}

// --------------------------- prep kernel -----------------------------------
// Fold BN into W1/b1; pack W1 (K 300->320) and W2 into bf16 MFMA-B-fragment
// order (frag block = contiguous 1KB; lane l holds B[k=(l>>4)*8+j][n=l&15]).
__global__ void prep_kernel(const float* __restrict__ W1, const float* __restrict__ b1,
                            const float* __restrict__ gamma, const float* __restrict__ beta,
                            const float* __restrict__ rmean, const float* __restrict__ rvar,
                            const float* __restrict__ W2,
                            unsigned short* __restrict__ w1p,
                            unsigned short* __restrict__ w2p,
                            float* __restrict__ b1p) {
    int idx = blockIdx.x * 256 + threadIdx.x;
    if (idx < 81920) {                       // W1 folded + packed
        int k = idx >> 8, n = idx & 255;
        float a = gamma[n] * __builtin_amdgcn_rsqf(rvar[n] + 1e-5f);
        float v = (k < 300) ? W1[k * HID_ + n] * a : 0.f;
        int blk = (k >> 5) * 16 + (n >> 4);
        int off = blk * 512 + (((k >> 3) & 3) * 16 + (n & 15)) * 8 + (k & 7);
        w1p[off] = bf16_bits(v);
    } else if (idx < 114688) {               // W2 packed
        int i2 = idx - 81920;
        int k = i2 >> 7, n = i2 & 127;
        int blk = (k >> 5) * 8 + (n >> 4);
        int off = blk * 512 + (((k >> 3) & 3) * 16 + (n & 15)) * 8 + (k & 7);
        w2p[off] = bf16_bits(W2[k * OUT_ + n]);
    } else if (idx < 114944) {               // folded bias
        int n = idx - 114688;
        float a = gamma[n] * __builtin_amdgcn_rsqf(rvar[n] + 1e-5f);
        b1p[n] = fmaf(a, b1[n] - rmean[n], beta[n]);
    }
}

// --------------------------- main fused kernel ------------------------------
// LDS: feat 64 x 328 ushort (41984B; reused as hidden 64 x 264)
//      rs[66] float4 (root.xyz, scale), jw[25]
#define LDS_FEAT 0
#define LDS_RS   41984                       // 16B aligned
#define LDS_JW   (LDS_RS + 66 * 16)          // 43040
#define LDS_TOT  (LDS_JW + 25 * 4 + 12)      // 43152 -> 3 blocks/CU, 24 waves

__global__ __launch_bounds__(TPB, 6) void pose_mlp(
    const float* __restrict__ poses,
    const unsigned short* __restrict__ w1p,
    const unsigned short* __restrict__ w2p,
    const float* __restrict__ b1p,
    const float* __restrict__ b2,
    const float* __restrict__ jw,
    float* __restrict__ out)
{
    __shared__ __align__(16) unsigned char smem[LDS_TOT];
    const int tid  = threadIdx.x;
    const int lane = tid & 63;
    const int wv   = tid >> 6;               // 0..7
    const int t0   = blockIdx.x * MT_;
    const int s0   = t0 & (S_ - 1);

    unsigned short* feat = (unsigned short*)(smem + LDS_FEAT);
    float4* rs  = (float4*)(smem + LDS_RS);
    float*  jwl = (float*)(smem + LDS_JW);

    // early prefetch: phase-1 kc=0 B-frags (this wave's 2 n-tiles) + biases
    short8 bw[2];
    #pragma unroll
    for (int ni = 0; ni < 2; ni++)
        bw[ni] = *(const short8*)(w1p + (unsigned)(wv * 2 + ni) * 512 + lane * 8);
    float bv[2];
    #pragma unroll
    for (int ni = 0; ni < 2; ni++) bv[ni] = b1p[wv * 32 + ni * 16 + (lane & 15)];
    float c2 = b2[wv * 16 + (lane & 15)];

    if (tid < 25) jwl[tid] = jw[tid];
    // zero constant-pad slots: angle slots j>=13 (36) + K-pad 300..327 (28)
    for (int i = tid; i < MT_ * 64; i += TPB) {
        int tt = i >> 6, z = i & 63;
        int k;
        if (z < 36) { int jj = z / 3; k = (13 + jj) * 12 + 9 + (z - jj * 3); }
        else        { k = 300 + z - 36; }
        feat[tt * 328 + k] = 0;
    }

    // ---- phase 0ab: root + scale per frame (66 frames x 4 lanes, shfl) ----
    if (tid < 264) {
        int f = tid >> 2, q = tid & 3;
        int g = t0 - 2 + f; if (g < 0) g = 0;        // clamped; masked later
        const float* P = poses + (size_t)g * 75;
        float r0 = P[0], r1 = P[1], r2 = P[2];
        float m2 = 0.f;
        #pragma unroll
        for (int jj = 0; jj < 7; jj++) {
            int j = q * 7 + jj;
            if (j < 25) {
                float dx = P[j*3]   - r0;
                float dy = P[j*3+1] - r1;
                float dz = P[j*3+2] - r2;
                m2 = fmaxf(m2, fmaf(dx, dx, fmaf(dy, dy, dz * dz)));
            }
        }
        m2 = fmaxf(m2, __shfl_xor(m2, 1));
        m2 = fmaxf(m2, __shfl_xor(m2, 2));
        if (q == 0) {
            float sc = __builtin_amdgcn_rcpf(__builtin_amdgcn_sqrtf(m2) + 1e-8f);
            rs[f] = make_float4(r0, r1, r2, sc);
        }
    }
    __syncthreads();

    // ---- phase 0c: pos/vel/acc per (token, joint) — 1600 items ----
    for (int i = tid; i < MT_ * 25; i += TPB) {
        int tt = i / 25, j = i - tt * 25;
        int s  = s0 + tt;
        int g  = t0 + tt;
        int g1 = g - 1 < 0 ? 0 : g - 1;
        int g2 = g - 2 < 0 ? 0 : g - 2;
        const float* Pc = poses + (size_t)g  * 75 + j * 3;
        const float* P1 = poses + (size_t)g1 * 75 + j * 3;
        const float* P2 = poses + (size_t)g2 * 75 + j * 3;
        float4 rc = rs[tt + 2], rm = rs[tt + 1], rp = rs[tt];
        float cx = (Pc[0] - rc.x) * rc.w, cy = (Pc[1] - rc.y) * rc.w, cz = (Pc[2] - rc.z) * rc.w;
        float mx = (P1[0] - rm.x) * rm.w, my = (P1[1] - rm.y) * rm.w, mz = (P1[2] - rm.z) * rm.w;
        float px = (P2[0] - rp.x) * rp.w, py = (P2[1] - rp.y) * rp.w, pz = (P2[2] - rp.z) * rp.w;
        bool h1 = (s >= 1), h2 = (s >= 2);
        float vx = h1 ? cx - mx : 0.f, vy = h1 ? cy - my : 0.f, vz = h1 ? cz - mz : 0.f;
        float ux = h2 ? mx - px : 0.f, uy = h2 ? my - py : 0.f, uz = h2 ? mz - pz : 0.f;
        float qx = vx - ux, qy = vy - uy, qz = vz - uz;   // acc (s==1 -> vel)
        float w = jwl[j];
        unsigned base = (unsigned)tt * 328 + j * 12;      // even -> dword aligned
        *(unsigned*)(feat + base)     = pkbf16(cx * w, cy * w);
        *(unsigned*)(feat + base + 2) = pkbf16(cz * w, vx * w);
        *(unsigned*)(feat + base + 4) = pkbf16(vy * w, vz * w);
        *(unsigned*)(feat + base + 6) = pkbf16(qx * w, qy * w);
        feat[base + 8] = bf16_bits(qz * w);
    }

    // ---- phase 0d: joint angles per (token, edge) — 832 items ----
    // v/||v|| invariant to centering + positive scale -> raw global coords
    for (int i = tid; i < MT_ * 13; i += TPB) {
        int tt = i / 13, e = i - tt * 13;
        int g  = t0 + tt;
        const float* P = poses + (size_t)g * 75;
        int a0 = (int)((C0M >> (4 * e)) & 15) * 3;
        int a1 = (((int)((C1M >> (4 * e)) & 15)) + 1) * 3;
        float vx = P[a1] - P[a0], vy = P[a1+1] - P[a0+1], vz = P[a1+2] - P[a0+2];
        float d  = fmaf(vx, vx, fmaf(vy, vy, vz * vz));
        float inv = __builtin_amdgcn_rcpf(fmaxf(__builtin_amdgcn_sqrtf(d), 1e-12f));
        float w = jwl[e];
        float A0 = facos(fminf(fmaxf(vx * inv, -1.f), 1.f)) * w;
        float A1 = facos(fminf(fmaxf(vy * inv, -1.f), 1.f)) * w;
        float A2 = facos(fminf(fmaxf(vz * inv, -1.f), 1.f)) * w;
        unsigned base = (unsigned)tt * 328 + e * 12 + 9;  // odd
        feat[base] = bf16_bits(A0);
        *(unsigned*)(feat + base + 1) = pkbf16(A1, A2);
    }
    __syncthreads();

    // ---- phase 1: hidden = relu(feat @ W1' + b1'); bias in MFMA C-in ----
    floatx4 acc[4][2];
    #pragma unroll
    for (int mi = 0; mi < 4; mi++)
        #pragma unroll
        for (int ni = 0; ni < 2; ni++)
            acc[mi][ni] = (floatx4){bv[ni], bv[ni], bv[ni], bv[ni]};

    #pragma unroll 1
    for (int kc = 0; kc < 10; kc++) {
        short8 bn[2];
        if (kc < 9) {
            #pragma unroll
            for (int ni = 0; ni < 2; ni++)
                bn[ni] = *(const short8*)(w1p + (unsigned)((kc + 1) * 16 + wv * 2 + ni) * 512 + lane * 8);
        }
        short8 af[4];
        #pragma unroll
        for (int mi = 0; mi < 4; mi++)   // A: row=(l&15)+16mi, k=kc*32+(l>>4)*8
            af[mi] = *(const short8*)(feat + (mi * 16 + (lane & 15)) * 328 + kc * 32 + (lane >> 4) * 8);
        #pragma unroll
        for (int mi = 0; mi < 4; mi++)
            #pragma unroll
            for (int ni = 0; ni < 2; ni++)
                acc[mi][ni] = __builtin_amdgcn_mfma_f32_16x16x32_bf16(
                    af[mi], bw[ni], acc[mi][ni], 0, 0, 0);
        if (kc < 9) {
            #pragma unroll
            for (int ni = 0; ni < 2; ni++) bw[ni] = bn[ni];
        }
    }

    // preload W2 kc=0 frag (this wave's n-tile), independent of LDS
    short8 bw2 = *(const short8*)(w2p + (unsigned)wv * 512 + lane * 8);

    __syncthreads();   // all waves done reading feat

    unsigned short* hid = feat;                            // reuse, stride 264
    #pragma unroll
    for (int mi = 0; mi < 4; mi++)
        #pragma unroll
        for (int ni = 0; ni < 2; ni++)
            #pragma unroll
            for (int r = 0; r < 4; r++) {
                float v = fmaxf(acc[mi][ni][r], 0.f);      // bias already in
                int m   = mi * 16 + (lane >> 4) * 4 + r;   // C/D: row=(l>>4)*4+r
                int col = wv * 32 + ni * 16 + (lane & 15); //      col=l&15
                hid[m * 264 + col] = bf16_bits(v);
            }
    __syncthreads();   // hid visible

    // ---- phase 2: out = hidden @ W2 + b2; wave wv owns n-tile wv ----
    floatx4 acc2[4];
    #pragma unroll
    for (int mi = 0; mi < 4; mi++) acc2[mi] = (floatx4){c2, c2, c2, c2};

    #pragma unroll 1
    for (int kc = 0; kc < 8; kc++) {
        short8 bn2;
        if (kc < 7)
            bn2 = *(const short8*)(w2p + (unsigned)((kc + 1) * 8 + wv) * 512 + lane * 8);
        short8 af[4];
        #pragma unroll
        for (int mi = 0; mi < 4; mi++)
            af[mi] = *(const short8*)(hid + (mi * 16 + (lane & 15)) * 264 + kc * 32 + (lane >> 4) * 8);
        #pragma unroll
        for (int mi = 0; mi < 4; mi++)
            acc2[mi] = __builtin_amdgcn_mfma_f32_16x16x32_bf16(
                af[mi], bw2, acc2[mi], 0, 0, 0);
        if (kc < 7) bw2 = bn2;
    }

    // ---- epilogue: direct stores (r4 addresses), NONTEMPORAL ----
    // each wave's store covers aligned 64B segments (col = wv*16 + l&15)
    #pragma unroll
    for (int mi = 0; mi < 4; mi++)
        #pragma unroll
        for (int r = 0; r < 4; r++) {
            int m   = mi * 16 + (lane >> 4) * 4 + r;
            int col = wv * 16 + (lane & 15);
            __builtin_nontemporal_store(acc2[mi][r],
                                        out + (size_t)(t0 + m) * OUT_ + col);
        }
}

// --------------------------- launch -----------------------------------------
extern "C" void kernel_launch(void* const* d_in, const int* in_sizes, int n_in,
                              void* d_out, int out_size, void* d_ws, size_t ws_size,
                              hipStream_t stream) {
    (void)in_sizes; (void)n_in; (void)out_size; (void)ws_size;
    const float* poses = (const float*)d_in[0];
    const float* W1    = (const float*)d_in[1];
    const float* b1    = (const float*)d_in[2];
    const float* gamma = (const float*)d_in[3];
    const float* beta  = (const float*)d_in[4];
    const float* rmean = (const float*)d_in[5];
    const float* rvar  = (const float*)d_in[6];
    const float* W2    = (const float*)d_in[7];
    const float* b2    = (const float*)d_in[8];
    const float* jw    = (const float*)d_in[9];

    unsigned short* w1p = (unsigned short*)d_ws;                 // 320*256 bf16
    unsigned short* w2p = w1p + 320 * HID_;                      // 256*128 bf16
    float* b1p = (float*)((char*)d_ws + (320 * HID_ + HID_ * OUT_) * 2);

    prep_kernel<<<449, 256, 0, stream>>>(W1, b1, gamma, beta, rmean, rvar, W2,
                                         w1p, w2p, b1p);
    pose_mlp<<<2048, TPB, 0, stream>>>(poses, w1p, w2p, b1p, b2, jw, (float*)d_out);
}